// Round 1
// baseline (1326.856 us; speedup 1.0000x reference)
//
#include <hip/hip_runtime.h>

// ---------------- problem constants ----------------
#define Bq    16
#define HRq   64
#define WRq   64
#define Cq    512
#define NHq   16
#define WSq   8
#define NTq   64      // tokens per window
#define TABq  15
#define DHq   32
#define Mq    65536   // total rows = B*HR*WR
// qkv row stride
#define QKVLD 1536

typedef __attribute__((ext_vector_type(8))) short   bfrag;   // 8 bf16 (4 VGPR)
typedef __attribute__((ext_vector_type(4))) float   facc;    // MFMA accum
typedef __attribute__((ext_vector_type(4))) float   f4v;
typedef __attribute__((ext_vector_type(8))) unsigned short u16x8;

__device__ __forceinline__ unsigned short f2bf(float f) {
  union { float f; unsigned int i; } c; c.f = f;
  unsigned int i = c.i;
  return (unsigned short)((i + 0x7FFFu + ((i >> 16) & 1u)) >> 16);  // RNE
}

// async global->LDS, 16B per lane; LDS base must be wave-uniform (HW adds lane*16)
#define GLD16(GP, LP) __builtin_amdgcn_global_load_lds(                         \
    (__attribute__((address_space(1))) void*)((void*)(GP)),                     \
    (__attribute__((address_space(3))) void*)((void*)(LP)), 16, 0, 0)

// ---------------- weight cast fp32 -> bf16 ----------------
__global__ __launch_bounds__(256) void cast_bf16_kernel(
    const float* __restrict__ s, unsigned short* __restrict__ d, int n4) {
  int i = blockIdx.x * 256 + threadIdx.x;
  if (i < n4) {
    f4v v = ((const f4v*)s)[i];
    unsigned short o0 = f2bf(v[0]), o1 = f2bf(v[1]), o2 = f2bf(v[2]), o3 = f2bf(v[3]);
    unsigned long long packed = (unsigned long long)o0 | ((unsigned long long)o1 << 16) |
                                ((unsigned long long)o2 << 32) | ((unsigned long long)o3 << 48);
    ((unsigned long long*)d)[i] = packed;
  }
}

// ---------------- relative-position bias: bias[h][i][j], (16,64,64) fp32 ----------------
__global__ __launch_bounds__(256) void bias_kernel(
    const float* __restrict__ a_p, const float* __restrict__ b_p,
    const float* __restrict__ a_r, const float* __restrict__ b_r,
    const int* __restrict__ ridx, const int* __restrict__ aidx,
    const float* __restrict__ theta, float* __restrict__ bias) {
  int t = blockIdx.x * 256 + threadIdx.x;    // 0..65535
  int h = t >> 12, ij = t & 4095;
  int ri = ridx[ij], ai = aidx[ij];
  float rel_r = (ri < WSq) ? (float)ri : (float)(ri - TABq);
  float rel_a = (ai < WSq) ? (float)ai : (float)(ai - TABq);
  float ph_a = rel_a * 6.283185307179586f / (float)WRq;
  float ph_r = rel_r * theta[0] / (float)HRq;
  float Aphi = a_p[ai * NHq + h] * cosf(ph_a) + b_p[ai * NHq + h] * sinf(ph_a);
  float Ath  = a_r[ri * NHq + h] * cosf(ph_r) + b_r[ri * NHq + h] * sinf(ph_r);
  bias[t] = Aphi + Ath;
}

// ---------------- layernorm (one wave per row), optional window-partition permute ----------------
template <int PERM>
__global__ __launch_bounds__(256) void ln_kernel(
    const float* __restrict__ x, const float* __restrict__ g, const float* __restrict__ b,
    unsigned short* __restrict__ out) {
  int row  = blockIdx.x * 4 + (threadIdx.x >> 6);
  int lane = threadIdx.x & 63;
  const float* xr = x + (size_t)row * Cq + lane * 8;
  f4v x0 = *(const f4v*)xr;
  f4v x1 = *(const f4v*)(xr + 4);
  float s = 0.f, q = 0.f;
#pragma unroll
  for (int e = 0; e < 4; ++e) { s += x0[e] + x1[e]; q += x0[e]*x0[e] + x1[e]*x1[e]; }
#pragma unroll
  for (int m = 1; m < 64; m <<= 1) { s += __shfl_xor(s, m, 64); q += __shfl_xor(q, m, 64); }
  float mu   = s * (1.0f / Cq);
  float var  = q * (1.0f / Cq) - mu * mu;
  float rstd = rsqrtf(var + 1e-5f);
  f4v g0 = *(const f4v*)(g + lane * 8);
  f4v g1 = *(const f4v*)(g + lane * 8 + 4);
  f4v b0 = *(const f4v*)(b + lane * 8);
  f4v b1 = *(const f4v*)(b + lane * 8 + 4);
  int orow = row;
  if (PERM) {  // original layout -> windowed layout
    int bb = row >> 12, y = (row >> 6) & 63, xx = row & 63;
    orow = ((bb * 8 + (y >> 3)) * 8 + (xx >> 3)) * 64 + ((y & 7) * 8 + (xx & 7));
  }
  u16x8 ov;
#pragma unroll
  for (int e = 0; e < 8; ++e) {
    float xe = (e < 4) ? x0[e] : x1[e - 4];
    float ge = (e < 4) ? g0[e] : g1[e - 4];
    float be = (e < 4) ? b0[e] : b1[e - 4];
    ov[e] = f2bf((xe - mu) * rstd * ge + be);
  }
  *(u16x8*)(out + (size_t)orow * Cq + lane * 8) = ov;
}

// ---------------- GEMM: out = A(MxK,bf16) * W(NxK,bf16)^T + bias, fused epilogues ----------------
// MODE 0: qkv   -> bf16 out (ld=1536)
// MODE 1: proj  -> fp32 d_out with window-reverse permute + residual add of x
// MODE 2: fc1   -> exact GELU -> bf16 out (ld=2048)
// MODE 3: fc2   -> d_out[row] += val (fp32)
template <int MODE>
__global__ __launch_bounds__(256) void gemm_bt_kernel(
    const unsigned short* __restrict__ A, const unsigned short* __restrict__ W,
    const float* __restrict__ bias, void* __restrict__ outp,
    const float* __restrict__ resid, int K, int ldo) {
  __shared__ unsigned short As[128 * 64];
  __shared__ unsigned short Bs[128 * 64];
  const int t = threadIdx.x;
  const int w = t >> 6;
  const int wr = w >> 1, wc = w & 1;
  const int l15 = t & 15, l4 = (t & 63) >> 4;
  const int tn = blockIdx.x * 128;
  const int tm = blockIdx.y * 128;

  facc zero = {0.f, 0.f, 0.f, 0.f};
  facc acc[4][4];
#pragma unroll
  for (int i = 0; i < 4; ++i)
#pragma unroll
    for (int j = 0; j < 4; ++j) acc[i][j] = zero;

  for (int k0 = 0; k0 < K; k0 += 64) {
#pragma unroll
    for (int i = 0; i < 4; ++i) {
      int c = (i << 8) + t;                  // chunk id 0..1023 (16B per chunk)
      int r = c >> 3, kc = (c & 7) << 3;
      // LDS base is wave-uniform; HW scatters +lane*16
      GLD16(A + (size_t)(tm + r) * K + (k0 + kc), As + (size_t)((i << 8) + (w << 6)) * 8);
      GLD16(W + (size_t)(tn + r) * K + (k0 + kc), Bs + (size_t)((i << 8) + (w << 6)) * 8);
    }
    __syncthreads();   // drains vmcnt for global_load_lds
#pragma unroll
    for (int kk = 0; kk < 64; kk += 32) {
      bfrag af[4], bf[4];
#pragma unroll
      for (int mt = 0; mt < 4; ++mt)
        af[mt] = *(const bfrag*)(As + (wr * 64 + mt * 16 + l15) * 64 + kk + l4 * 8);
#pragma unroll
      for (int nt = 0; nt < 4; ++nt)
        bf[nt] = *(const bfrag*)(Bs + (wc * 64 + nt * 16 + l15) * 64 + kk + l4 * 8);
#pragma unroll
      for (int mt = 0; mt < 4; ++mt)
#pragma unroll
        for (int nt = 0; nt < 4; ++nt)
          acc[mt][nt] = __builtin_amdgcn_mfma_f32_16x16x32_bf16(af[mt], bf[nt], acc[mt][nt], 0, 0, 0);
    }
    __syncthreads();
  }

#pragma unroll
  for (int mt = 0; mt < 4; ++mt) {
#pragma unroll
    for (int nt = 0; nt < 4; ++nt) {
      int col = tn + wc * 64 + nt * 16 + l15;
      float bval = bias[col];
#pragma unroll
      for (int r = 0; r < 4; ++r) {
        int row = tm + wr * 64 + mt * 16 + l4 * 4 + r;
        float v = acc[mt][nt][r] + bval;
        if constexpr (MODE == 0) {
          ((unsigned short*)outp)[(size_t)row * ldo + col] = f2bf(v);
        } else if constexpr (MODE == 1) {
          // windowed row -> original row (window reverse), + residual
          int wm = row >> 6, tt = row & 63;
          int bb = wm >> 6, hw = (wm >> 3) & 7, ww = wm & 7;
          int orow = bb * 4096 + ((hw * 8 + (tt >> 3)) << 6) + ww * 8 + (tt & 7);
          float res = resid[(size_t)orow * ldo + col];
          ((float*)outp)[(size_t)orow * ldo + col] = v + res;
        } else if constexpr (MODE == 2) {
          float gl = 0.5f * v * (1.0f + erff(v * 0.7071067811865475f));
          ((unsigned short*)outp)[(size_t)row * ldo + col] = f2bf(gl);
        } else {
          float* o = (float*)outp + (size_t)row * ldo + col;
          *o += v;
        }
      }
    }
  }
}

// ---------------- fused window attention: one wave per (window, head) ----------------
__global__ __launch_bounds__(64) void attn_kernel(
    const unsigned short* __restrict__ qkv, const float* __restrict__ bias,
    unsigned short* __restrict__ outp) {
  __shared__ unsigned short P[64 * 64];   // swizzled P (bf16)
  __shared__ unsigned short V[64 * 32];   // V linear [token][dh]
  const int lane = threadIdx.x;
  const int l15 = lane & 15, l4 = lane >> 4;
  const int win = blockIdx.x >> 4, h = blockIdx.x & 15;
  const unsigned short* qb = qkv + (size_t)(win * 64) * QKVLD + h * 32;
  const unsigned short* kb = qb + 512;
  const unsigned short* vb = qb + 1024;

  // stage V async (overlaps QK^T + softmax)
#pragma unroll
  for (int i = 0; i < 4; ++i) {
    int c = i * 64 + lane;          // 16B chunk id; row = c>>2, colchunk = c&3
    int r = c >> 2, kc = (c & 3) << 3;
    GLD16(vb + (size_t)r * QKVLD + kc, V + (size_t)i * 512);
  }

  // QK^T (K = DH = 32 -> single MFMA k-step)
  bfrag qf[4], kf[4];
#pragma unroll
  for (int mt = 0; mt < 4; ++mt)
    qf[mt] = *(const bfrag*)(qb + (size_t)(mt * 16 + l15) * QKVLD + l4 * 8);
#pragma unroll
  for (int nt = 0; nt < 4; ++nt)
    kf[nt] = *(const bfrag*)(kb + (size_t)(nt * 16 + l15) * QKVLD + l4 * 8);
  facc zero = {0.f, 0.f, 0.f, 0.f};
  facc s[4][4];
#pragma unroll
  for (int mt = 0; mt < 4; ++mt)
#pragma unroll
    for (int nt = 0; nt < 4; ++nt) {
      s[mt][nt] = zero;
      s[mt][nt] = __builtin_amdgcn_mfma_f32_16x16x32_bf16(qf[mt], kf[nt], s[mt][nt], 0, 0, 0);
    }

  // scale + bias + softmax (unnormalized; 1/sum deferred to epilogue)
  const float scale = 0.17677669529663687f;   // 32^-0.5
  const float* bb = bias + h * 4096;
  float rinv[4][4];
#pragma unroll
  for (int mt = 0; mt < 4; ++mt) {
#pragma unroll
    for (int r = 0; r < 4; ++r) {
      int i = mt * 16 + l4 * 4 + r;
#pragma unroll
      for (int jt = 0; jt < 4; ++jt) {
        int j = jt * 16 + l15;
        s[mt][jt][r] = s[mt][jt][r] * scale + bb[i * 64 + j];
      }
      float rm = fmaxf(fmaxf(s[mt][0][r], s[mt][1][r]), fmaxf(s[mt][2][r], s[mt][3][r]));
      rm = fmaxf(rm, __shfl_xor(rm, 1, 64));
      rm = fmaxf(rm, __shfl_xor(rm, 2, 64));
      rm = fmaxf(rm, __shfl_xor(rm, 4, 64));
      rm = fmaxf(rm, __shfl_xor(rm, 8, 64));
      float sum = 0.f;
#pragma unroll
      for (int jt = 0; jt < 4; ++jt) {
        float e = __expf(s[mt][jt][r] - rm);
        s[mt][jt][r] = e;
        sum += e;
      }
      sum += __shfl_xor(sum, 1, 64);
      sum += __shfl_xor(sum, 2, 64);
      sum += __shfl_xor(sum, 4, 64);
      sum += __shfl_xor(sum, 8, 64);
      rinv[mt][r] = 1.0f / sum;
    }
  }

  // write P to LDS, XOR-swizzled to kill the 16-way row-stride bank conflict on read
#pragma unroll
  for (int mt = 0; mt < 4; ++mt)
#pragma unroll
    for (int jt = 0; jt < 4; ++jt)
#pragma unroll
      for (int r = 0; r < 4; ++r) {
        int i = mt * 16 + l4 * 4 + r, j = jt * 16 + l15;
        int bofs = (i * 128 + j * 2) ^ ((i & 7) << 4);
        *(unsigned short*)((char*)P + bofs) = f2bf(s[mt][jt][r]);
      }
  __syncthreads();   // also drains V's global_load_lds

  // PV: O[i][d] = sum_j P[i][j] * V[j][d]   (M=64, N=32, K=64)
  facc o[4][2];
#pragma unroll
  for (int mt = 0; mt < 4; ++mt)
#pragma unroll
    for (int nt = 0; nt < 2; ++nt) o[mt][nt] = zero;
#pragma unroll
  for (int kt = 0; kt < 2; ++kt) {
    bfrag pf[4];
#pragma unroll
    for (int mt = 0; mt < 4; ++mt) {
      int row = mt * 16 + l15;
      int bofs = (row * 128 + (kt * 32 + l4 * 8) * 2) ^ ((row & 7) << 4);
      pf[mt] = *(const bfrag*)((char*)P + bofs);
    }
    bfrag vf[2];
#pragma unroll
    for (int nt = 0; nt < 2; ++nt) {
      bfrag tv;
#pragma unroll
      for (int e = 0; e < 8; ++e) {
        int j = kt * 32 + l4 * 8 + e;
        tv[e] = (short)V[j * 32 + nt * 16 + l15];
      }
      vf[nt] = tv;
    }
#pragma unroll
    for (int mt = 0; mt < 4; ++mt)
#pragma unroll
      for (int nt = 0; nt < 2; ++nt)
        o[mt][nt] = __builtin_amdgcn_mfma_f32_16x16x32_bf16(pf[mt], vf[nt], o[mt][nt], 0, 0, 0);
  }

  // normalize + store bf16 (windowed layout, heads interleaved: col = h*32+d)
#pragma unroll
  for (int mt = 0; mt < 4; ++mt)
#pragma unroll
    for (int nt = 0; nt < 2; ++nt)
#pragma unroll
      for (int r = 0; r < 4; ++r) {
        int i = mt * 16 + l4 * 4 + r, d = nt * 16 + l15;
        float val = o[mt][nt][r] * rinv[mt][r];
        outp[(size_t)(win * 64 + i) * Cq + h * 32 + d] = f2bf(val);
      }
}

// ---------------- launch ----------------
extern "C" void kernel_launch(void* const* d_in, const int* in_sizes, int n_in,
                              void* d_out, int out_size, void* d_ws, size_t ws_size,
                              hipStream_t stream) {
  const float* x     = (const float*)d_in[0];
  const float* theta = (const float*)d_in[1];
  const float* n1g   = (const float*)d_in[2];
  const float* n1b   = (const float*)d_in[3];
  const float* qkvw  = (const float*)d_in[4];
  const float* qkvb  = (const float*)d_in[5];
  const float* a_p   = (const float*)d_in[6];
  const float* b_p   = (const float*)d_in[7];
  const float* a_r   = (const float*)d_in[8];
  const float* b_r   = (const float*)d_in[9];
  const float* projw = (const float*)d_in[10];
  const float* projb = (const float*)d_in[11];
  const float* n2g   = (const float*)d_in[12];
  const float* n2b   = (const float*)d_in[13];
  const float* fc1w  = (const float*)d_in[14];
  const float* fc1b  = (const float*)d_in[15];
  const float* fc2w  = (const float*)d_in[16];
  const float* fc2b  = (const float*)d_in[17];
  const int* ridx    = (const int*)d_in[18];
  const int* aidx    = (const int*)d_in[19];
  float* out = (float*)d_out;

  // workspace layout (bytes); fc1buf reuses qkv+attn regions (dead by then)
  char* ws = (char*)d_ws;
  unsigned short* lnbuf   = (unsigned short*)(ws);                   //  67108864 B (ln1, later ln2)
  unsigned short* qkvbuf  = (unsigned short*)(ws + 67108864LL);      // 201326592 B
  unsigned short* attnbuf = (unsigned short*)(ws + 268435456LL);     //  67108864 B
  unsigned short* fc1buf  = (unsigned short*)(ws + 67108864LL);      // 268435456 B (overlap ok)
  unsigned short* wq  = (unsigned short*)(ws + 335544320LL);
  unsigned short* wp  = (unsigned short*)(ws + 337117184LL);
  unsigned short* wf1 = (unsigned short*)(ws + 337641472LL);
  unsigned short* wf2 = (unsigned short*)(ws + 339738624LL);
  float* biasbuf = (float*)(ws + 341835776LL);                       // 262144 B -> total ~342 MB

  cast_bf16_kernel<<<768, 256, 0, stream>>>(qkvw, wq, 786432 / 4);
  cast_bf16_kernel<<<256, 256, 0, stream>>>(projw, wp, 262144 / 4);
  cast_bf16_kernel<<<1024, 256, 0, stream>>>(fc1w, wf1, 1048576 / 4);
  cast_bf16_kernel<<<1024, 256, 0, stream>>>(fc2w, wf2, 1048576 / 4);
  bias_kernel<<<256, 256, 0, stream>>>(a_p, b_p, a_r, b_r, ridx, aidx, theta, biasbuf);

  ln_kernel<1><<<16384, 256, 0, stream>>>(x, n1g, n1b, lnbuf);
  gemm_bt_kernel<0><<<dim3(12, 512), 256, 0, stream>>>(lnbuf, wq, qkvb, qkvbuf, nullptr, 512, QKVLD);
  attn_kernel<<<16384, 64, 0, stream>>>(qkvbuf, biasbuf, attnbuf);
  gemm_bt_kernel<1><<<dim3(4, 512), 256, 0, stream>>>(attnbuf, wp, projb, out, x, 512, 512);
  ln_kernel<0><<<16384, 256, 0, stream>>>(out, n2g, n2b, lnbuf);
  gemm_bt_kernel<2><<<dim3(16, 512), 256, 0, stream>>>(lnbuf, wf1, fc1b, fc1buf, nullptr, 512, 2048);
  gemm_bt_kernel<3><<<dim3(4, 512), 256, 0, stream>>>(fc1buf, wf2, fc2b, out, nullptr, 2048, 512);
}

// Round 6
// 1241.346 us; speedup vs baseline: 1.0689x; 1.0689x over previous
//
#include <hip/hip_runtime.h>

// ---------------- problem constants ----------------
#define Bq    16
#define HRq   64
#define WRq   64
#define Cq    512
#define NHq   16
#define WSq   8
#define NTq   64      // tokens per window
#define TABq  15
#define DHq   32
#define Mq    65536   // total rows = B*HR*WR
// qkv row stride
#define QKVLD 1536

typedef __attribute__((ext_vector_type(8))) short   bfrag;   // 8 bf16 (4 VGPR)
typedef __attribute__((ext_vector_type(4))) float   facc;    // MFMA accum
typedef __attribute__((ext_vector_type(4))) float   f4v;
typedef __attribute__((ext_vector_type(8))) unsigned short u16x8;

__device__ __forceinline__ unsigned short f2bf(float f) {
  union { float f; unsigned int i; } c; c.f = f;
  unsigned int i = c.i;
  return (unsigned short)((i + 0x7FFFu + ((i >> 16) & 1u)) >> 16);  // RNE
}

// async global->LDS, 16B per lane; LDS base must be wave-uniform (HW adds lane*16)
#define GLD16(GP, LP) __builtin_amdgcn_global_load_lds(                         \
    (__attribute__((address_space(1))) void*)((void*)(GP)),                     \
    (__attribute__((address_space(3))) void*)((void*)(LP)), 16, 0, 0)

// XCD-aware bijective block remap (T1/m157): consecutive LOGICAL blocks land on
// the same XCD's L2. Requires gridDim.x*gridDim.y % 8 == 0 (all our grids are).
__device__ __forceinline__ void xcd_remap(int& bx, int& by) {
  int gx = gridDim.x;
  int nwg = gx * gridDim.y;
  int d = by * gx + bx;          // hw dispatch-linear id (x fastest)
  int cpx = nwg >> 3;
  int l = (d & 7) * cpx + (d >> 3);
  bx = l % gx;
  by = l / gx;
}

// ---------------- weight cast fp32 -> bf16 ----------------
__global__ __launch_bounds__(256) void cast_bf16_kernel(
    const float* __restrict__ s, unsigned short* __restrict__ d, int n4) {
  int i = blockIdx.x * 256 + threadIdx.x;
  if (i < n4) {
    f4v v = ((const f4v*)s)[i];
    unsigned short o0 = f2bf(v[0]), o1 = f2bf(v[1]), o2 = f2bf(v[2]), o3 = f2bf(v[3]);
    unsigned long long packed = (unsigned long long)o0 | ((unsigned long long)o1 << 16) |
                                ((unsigned long long)o2 << 32) | ((unsigned long long)o3 << 48);
    ((unsigned long long*)d)[i] = packed;
  }
}

// ---------------- relative-position bias: bias[h][i][j], (16,64,64) fp32 ----------------
__global__ __launch_bounds__(256) void bias_kernel(
    const float* __restrict__ a_p, const float* __restrict__ b_p,
    const float* __restrict__ a_r, const float* __restrict__ b_r,
    const int* __restrict__ ridx, const int* __restrict__ aidx,
    const float* __restrict__ theta, float* __restrict__ bias) {
  int t = blockIdx.x * 256 + threadIdx.x;    // 0..65535
  int h = t >> 12, ij = t & 4095;
  int ri = ridx[ij], ai = aidx[ij];
  float rel_r = (ri < WSq) ? (float)ri : (float)(ri - TABq);
  float rel_a = (ai < WSq) ? (float)ai : (float)(ai - TABq);
  float ph_a = rel_a * 6.283185307179586f / (float)WRq;
  float ph_r = rel_r * theta[0] / (float)HRq;
  float Aphi = a_p[ai * NHq + h] * cosf(ph_a) + b_p[ai * NHq + h] * sinf(ph_a);
  float Ath  = a_r[ri * NHq + h] * cosf(ph_r) + b_r[ri * NHq + h] * sinf(ph_r);
  bias[t] = Aphi + Ath;
}

// ---------------- layernorm (one wave per row), optional window-partition permute ----------------
template <int PERM>
__global__ __launch_bounds__(256) void ln_kernel(
    const float* __restrict__ x, const float* __restrict__ g, const float* __restrict__ b,
    unsigned short* __restrict__ out) {
  int row  = blockIdx.x * 4 + (threadIdx.x >> 6);
  int lane = threadIdx.x & 63;
  const float* xr = x + (size_t)row * Cq + lane * 8;
  f4v x0 = *(const f4v*)xr;
  f4v x1 = *(const f4v*)(xr + 4);
  float s = 0.f, q = 0.f;
#pragma unroll
  for (int e = 0; e < 4; ++e) { s += x0[e] + x1[e]; q += x0[e]*x0[e] + x1[e]*x1[e]; }
#pragma unroll
  for (int m = 1; m < 64; m <<= 1) { s += __shfl_xor(s, m, 64); q += __shfl_xor(q, m, 64); }
  float mu   = s * (1.0f / Cq);
  float var  = q * (1.0f / Cq) - mu * mu;
  float rstd = rsqrtf(var + 1e-5f);
  f4v g0 = *(const f4v*)(g + lane * 8);
  f4v g1 = *(const f4v*)(g + lane * 8 + 4);
  f4v b0 = *(const f4v*)(b + lane * 8);
  f4v b1 = *(const f4v*)(b + lane * 8 + 4);
  int orow = row;
  if (PERM) {  // original layout -> windowed layout
    int bb = row >> 12, y = (row >> 6) & 63, xx = row & 63;
    orow = ((bb * 8 + (y >> 3)) * 8 + (xx >> 3)) * 64 + ((y & 7) * 8 + (xx & 7));
  }
  u16x8 ov;
#pragma unroll
  for (int e = 0; e < 8; ++e) {
    float xe = (e < 4) ? x0[e] : x1[e - 4];
    float ge = (e < 4) ? g0[e] : g1[e - 4];
    float be = (e < 4) ? b0[e] : b1[e - 4];
    ov[e] = f2bf((xe - mu) * rstd * ge + be);
  }
  *(u16x8*)(out + (size_t)orow * Cq + lane * 8) = ov;
}

// ---------------- GEMM: out = A(MxK,bf16) * W(NxK,bf16)^T + bias, fused epilogues ----------------
// 128x128 tile, 4 waves. MODE 0: qkv -> bf16 (ld=1536). MODE 1: proj -> fp32 d_out
// with window-reverse + residual. MODE 2: fc1 -> GELU -> bf16 (ld=2048).
template <int MODE>
__global__ __launch_bounds__(256) void gemm_bt_kernel(
    const unsigned short* __restrict__ A, const unsigned short* __restrict__ W,
    const float* __restrict__ bias, void* __restrict__ outp,
    const float* __restrict__ resid, int K, int ldo) {
  __shared__ unsigned short As[128 * 64];
  __shared__ unsigned short Bs[128 * 64];
  const int t = threadIdx.x;
  const int w = t >> 6;
  const int wr = w >> 1, wc = w & 1;
  const int l15 = t & 15, l4 = (t & 63) >> 4;
  int bx = blockIdx.x, by = blockIdx.y;
  xcd_remap(bx, by);
  const int tn = bx * 128;
  const int tm = by * 128;

  facc zero = {0.f, 0.f, 0.f, 0.f};
  facc acc[4][4];
#pragma unroll
  for (int i = 0; i < 4; ++i)
#pragma unroll
    for (int j = 0; j < 4; ++j) acc[i][j] = zero;

  for (int k0 = 0; k0 < K; k0 += 64) {
#pragma unroll
    for (int i = 0; i < 4; ++i) {
      int c = (i << 8) + t;                  // chunk id 0..1023 (16B per chunk)
      int r = c >> 3, kc = (c & 7) << 3;
      // LDS base is wave-uniform; HW scatters +lane*16
      GLD16(A + (size_t)(tm + r) * K + (k0 + kc), As + (size_t)((i << 8) + (w << 6)) * 8);
      GLD16(W + (size_t)(tn + r) * K + (k0 + kc), Bs + (size_t)((i << 8) + (w << 6)) * 8);
    }
    __syncthreads();   // drains vmcnt for global_load_lds
#pragma unroll
    for (int kk = 0; kk < 64; kk += 32) {
      bfrag af[4], bf[4];
#pragma unroll
      for (int mt = 0; mt < 4; ++mt)
        af[mt] = *(const bfrag*)(As + (wr * 64 + mt * 16 + l15) * 64 + kk + l4 * 8);
#pragma unroll
      for (int nt = 0; nt < 4; ++nt)
        bf[nt] = *(const bfrag*)(Bs + (wc * 64 + nt * 16 + l15) * 64 + kk + l4 * 8);
#pragma unroll
      for (int mt = 0; mt < 4; ++mt)
#pragma unroll
        for (int nt = 0; nt < 4; ++nt)
          acc[mt][nt] = __builtin_amdgcn_mfma_f32_16x16x32_bf16(af[mt], bf[nt], acc[mt][nt], 0, 0, 0);
    }
    __syncthreads();
  }

#pragma unroll
  for (int mt = 0; mt < 4; ++mt) {
#pragma unroll
    for (int nt = 0; nt < 4; ++nt) {
      int col = tn + wc * 64 + nt * 16 + l15;
      float bval = bias[col];
#pragma unroll
      for (int r = 0; r < 4; ++r) {
        int row = tm + wr * 64 + mt * 16 + l4 * 4 + r;
        float v = acc[mt][nt][r] + bval;
        if constexpr (MODE == 0) {
          ((unsigned short*)outp)[(size_t)row * ldo + col] = f2bf(v);
        } else if constexpr (MODE == 1) {
          // windowed row -> original row (window reverse), + residual
          int wm = row >> 6, tt = row & 63;
          int bb = wm >> 6, hw = (wm >> 3) & 7, ww = wm & 7;
          int orow = bb * 4096 + ((hw * 8 + (tt >> 3)) << 6) + ww * 8 + (tt & 7);
          float res = resid[(size_t)orow * ldo + col];
          ((float*)outp)[(size_t)orow * ldo + col] = v + res;
        } else if constexpr (MODE == 2) {
          float gl = 0.5f * v * (1.0f + erff(v * 0.7071067811865475f));
          ((unsigned short*)outp)[(size_t)row * ldo + col] = f2bf(gl);
        }
      }
    }
  }
}

// ---------------- fc2 GEMM: 128x256 tile, 8 waves (2M x 4N), out += A*W^T + bias ----------------
// A is 256 MB (doesn't fit L3) -> BN=256 halves A re-fetch (2 N-tiles instead of 4);
// XCD remap co-locates both N-tiles of an M-panel on one XCD L2.
__global__ __launch_bounds__(512) void gemm_fc2_kernel(
    const unsigned short* __restrict__ A, const unsigned short* __restrict__ W,
    const float* __restrict__ bias, float* __restrict__ outp, int K, int ldo) {
  __shared__ unsigned short As[128 * 64];   // 16 KB
  __shared__ unsigned short Bs[256 * 64];   // 32 KB
  const int t = threadIdx.x;
  const int w = t >> 6;                     // 0..7
  const int wr = w >> 2, wc = w & 3;        // 2 M-halves x 4 N-quarters
  const int l15 = t & 15, l4 = (t & 63) >> 4;
  int bx = blockIdx.x, by = blockIdx.y;
  xcd_remap(bx, by);
  const int tn = bx * 256;
  const int tm = by * 128;

  facc zero = {0.f, 0.f, 0.f, 0.f};
  facc acc[4][4];
#pragma unroll
  for (int i = 0; i < 4; ++i)
#pragma unroll
    for (int j = 0; j < 4; ++j) acc[i][j] = zero;

  for (int k0 = 0; k0 < K; k0 += 64) {
    // A: 128x64 = 1024 chunks, 2 iters over 512 lanes
#pragma unroll
    for (int i = 0; i < 2; ++i) {
      int c = (i << 9) + t;
      int r = c >> 3, kc = (c & 7) << 3;
      GLD16(A + (size_t)(tm + r) * K + (k0 + kc), As + (size_t)((i << 9) + (w << 6)) * 8);
    }
    // B: 256x64 = 2048 chunks, 4 iters
#pragma unroll
    for (int i = 0; i < 4; ++i) {
      int c = (i << 9) + t;
      int r = c >> 3, kc = (c & 7) << 3;
      GLD16(W + (size_t)(tn + r) * K + (k0 + kc), Bs + (size_t)((i << 9) + (w << 6)) * 8);
    }
    __syncthreads();
#pragma unroll
    for (int kk = 0; kk < 64; kk += 32) {
      bfrag af[4], bf[4];
#pragma unroll
      for (int mt = 0; mt < 4; ++mt)
        af[mt] = *(const bfrag*)(As + (wr * 64 + mt * 16 + l15) * 64 + kk + l4 * 8);
#pragma unroll
      for (int nt = 0; nt < 4; ++nt)
        bf[nt] = *(const bfrag*)(Bs + (wc * 64 + nt * 16 + l15) * 64 + kk + l4 * 8);
#pragma unroll
      for (int mt = 0; mt < 4; ++mt)
#pragma unroll
        for (int nt = 0; nt < 4; ++nt)
          acc[mt][nt] = __builtin_amdgcn_mfma_f32_16x16x32_bf16(af[mt], bf[nt], acc[mt][nt], 0, 0, 0);
    }
    __syncthreads();
  }

#pragma unroll
  for (int mt = 0; mt < 4; ++mt) {
#pragma unroll
    for (int nt = 0; nt < 4; ++nt) {
      int col = tn + wc * 64 + nt * 16 + l15;
      float bval = bias[col];
#pragma unroll
      for (int r = 0; r < 4; ++r) {
        int row = tm + wr * 64 + mt * 16 + l4 * 4 + r;
        float* o = outp + (size_t)row * ldo + col;
        *o += acc[mt][nt][r] + bval;
      }
    }
  }
}

// ---------------- fused window attention: one wave per (window, head) ----------------
__global__ __launch_bounds__(64) void attn_kernel(
    const unsigned short* __restrict__ qkv, const float* __restrict__ bias,
    unsigned short* __restrict__ outp) {
  __shared__ unsigned short P[64 * 64];   // swizzled P (bf16)
  __shared__ unsigned short V[64 * 32];   // V linear [token][dh]
  const int lane = threadIdx.x;
  const int l15 = lane & 15, l4 = lane >> 4;
  const int win = blockIdx.x >> 4, h = blockIdx.x & 15;
  const unsigned short* qb = qkv + (size_t)(win * 64) * QKVLD + h * 32;
  const unsigned short* kb = qb + 512;
  const unsigned short* vb = qb + 1024;

  // stage V async (overlaps QK^T + softmax)
#pragma unroll
  for (int i = 0; i < 4; ++i) {
    int c = i * 64 + lane;          // 16B chunk id; row = c>>2, colchunk = c&3
    int r = c >> 2, kc = (c & 3) << 3;
    GLD16(vb + (size_t)r * QKVLD + kc, V + (size_t)i * 512);
  }

  // QK^T (K = DH = 32 -> single MFMA k-step)
  bfrag qf[4], kf[4];
#pragma unroll
  for (int mt = 0; mt < 4; ++mt)
    qf[mt] = *(const bfrag*)(qb + (size_t)(mt * 16 + l15) * QKVLD + l4 * 8);
#pragma unroll
  for (int nt = 0; nt < 4; ++nt)
    kf[nt] = *(const bfrag*)(kb + (size_t)(nt * 16 + l15) * QKVLD + l4 * 8);
  facc zero = {0.f, 0.f, 0.f, 0.f};
  facc s[4][4];
#pragma unroll
  for (int mt = 0; mt < 4; ++mt)
#pragma unroll
    for (int nt = 0; nt < 4; ++nt) {
      s[mt][nt] = zero;
      s[mt][nt] = __builtin_amdgcn_mfma_f32_16x16x32_bf16(qf[mt], kf[nt], s[mt][nt], 0, 0, 0);
    }

  // scale + bias + softmax (unnormalized; 1/sum deferred to epilogue)
  const float scale = 0.17677669529663687f;   // 32^-0.5
  const float* bb = bias + h * 4096;
  float rinv[4][4];
#pragma unroll
  for (int mt = 0; mt < 4; ++mt) {
#pragma unroll
    for (int r = 0; r < 4; ++r) {
      int i = mt * 16 + l4 * 4 + r;
#pragma unroll
      for (int jt = 0; jt < 4; ++jt) {
        int j = jt * 16 + l15;
        s[mt][jt][r] = s[mt][jt][r] * scale + bb[i * 64 + j];
      }
      float rm = fmaxf(fmaxf(s[mt][0][r], s[mt][1][r]), fmaxf(s[mt][2][r], s[mt][3][r]));
      rm = fmaxf(rm, __shfl_xor(rm, 1, 64));
      rm = fmaxf(rm, __shfl_xor(rm, 2, 64));
      rm = fmaxf(rm, __shfl_xor(rm, 4, 64));
      rm = fmaxf(rm, __shfl_xor(rm, 8, 64));
      float sum = 0.f;
#pragma unroll
      for (int jt = 0; jt < 4; ++jt) {
        float e = __expf(s[mt][jt][r] - rm);
        s[mt][jt][r] = e;
        sum += e;
      }
      sum += __shfl_xor(sum, 1, 64);
      sum += __shfl_xor(sum, 2, 64);
      sum += __shfl_xor(sum, 4, 64);
      sum += __shfl_xor(sum, 8, 64);
      rinv[mt][r] = 1.0f / sum;
    }
  }

  // write P to LDS, XOR-swizzled to kill the 16-way row-stride bank conflict on read
#pragma unroll
  for (int mt = 0; mt < 4; ++mt)
#pragma unroll
    for (int jt = 0; jt < 4; ++jt)
#pragma unroll
      for (int r = 0; r < 4; ++r) {
        int i = mt * 16 + l4 * 4 + r, j = jt * 16 + l15;
        int bofs = (i * 128 + j * 2) ^ ((i & 7) << 4);
        *(unsigned short*)((char*)P + bofs) = f2bf(s[mt][jt][r]);
      }
  __syncthreads();   // also drains V's global_load_lds

  // PV: O[i][d] = sum_j P[i][j] * V[j][d]   (M=64, N=32, K=64)
  facc o[4][2];
#pragma unroll
  for (int mt = 0; mt < 4; ++mt)
#pragma unroll
    for (int nt = 0; nt < 2; ++nt) o[mt][nt] = zero;
#pragma unroll
  for (int kt = 0; kt < 2; ++kt) {
    bfrag pf[4];
#pragma unroll
    for (int mt = 0; mt < 4; ++mt) {
      int row = mt * 16 + l15;
      int bofs = (row * 128 + (kt * 32 + l4 * 8) * 2) ^ ((row & 7) << 4);
      pf[mt] = *(const bfrag*)((char*)P + bofs);
    }
    bfrag vf[2];
#pragma unroll
    for (int nt = 0; nt < 2; ++nt) {
      bfrag tv;
#pragma unroll
      for (int e = 0; e < 8; ++e) {
        int j = kt * 32 + l4 * 8 + e;
        tv[e] = (short)V[j * 32 + nt * 16 + l15];
      }
      vf[nt] = tv;
    }
#pragma unroll
    for (int mt = 0; mt < 4; ++mt)
#pragma unroll
      for (int nt = 0; nt < 2; ++nt)
        o[mt][nt] = __builtin_amdgcn_mfma_f32_16x16x32_bf16(pf[mt], vf[nt], o[mt][nt], 0, 0, 0);
  }

  // normalize + store bf16 (windowed layout, heads interleaved: col = h*32+d)
#pragma unroll
  for (int mt = 0; mt < 4; ++mt)
#pragma unroll
    for (int nt = 0; nt < 2; ++nt)
#pragma unroll
      for (int r = 0; r < 4; ++r) {
        int i = mt * 16 + l4 * 4 + r, d = nt * 16 + l15;
        float val = o[mt][nt][r] * rinv[mt][r];
        outp[(size_t)(win * 64 + i) * Cq + h * 32 + d] = f2bf(val);
      }
}

// ---------------- launch ----------------
extern "C" void kernel_launch(void* const* d_in, const int* in_sizes, int n_in,
                              void* d_out, int out_size, void* d_ws, size_t ws_size,
                              hipStream_t stream) {
  const float* x     = (const float*)d_in[0];
  const float* theta = (const float*)d_in[1];
  const float* n1g   = (const float*)d_in[2];
  const float* n1b   = (const float*)d_in[3];
  const float* qkvw  = (const float*)d_in[4];
  const float* qkvb  = (const float*)d_in[5];
  const float* a_p   = (const float*)d_in[6];
  const float* b_p   = (const float*)d_in[7];
  const float* a_r   = (const float*)d_in[8];
  const float* b_r   = (const float*)d_in[9];
  const float* projw = (const float*)d_in[10];
  const float* projb = (const float*)d_in[11];
  const float* n2g   = (const float*)d_in[12];
  const float* n2b   = (const float*)d_in[13];
  const float* fc1w  = (const float*)d_in[14];
  const float* fc1b  = (const float*)d_in[15];
  const float* fc2w  = (const float*)d_in[16];
  const float* fc2b  = (const float*)d_in[17];
  const int* ridx    = (const int*)d_in[18];
  const int* aidx    = (const int*)d_in[19];
  float* out = (float*)d_out;

  // workspace layout (bytes); fc1buf reuses qkv+attn regions (dead by then)
  char* ws = (char*)d_ws;
  unsigned short* lnbuf   = (unsigned short*)(ws);                   //  67108864 B (ln1, later ln2)
  unsigned short* qkvbuf  = (unsigned short*)(ws + 67108864LL);      // 201326592 B
  unsigned short* attnbuf = (unsigned short*)(ws + 268435456LL);     //  67108864 B
  unsigned short* fc1buf  = (unsigned short*)(ws + 67108864LL);      // 268435456 B (overlap ok)
  unsigned short* wq  = (unsigned short*)(ws + 335544320LL);
  unsigned short* wp  = (unsigned short*)(ws + 337117184LL);
  unsigned short* wf1 = (unsigned short*)(ws + 337641472LL);
  unsigned short* wf2 = (unsigned short*)(ws + 339738624LL);
  float* biasbuf = (float*)(ws + 341835776LL);                       // 262144 B -> total ~342 MB

  cast_bf16_kernel<<<768, 256, 0, stream>>>(qkvw, wq, 786432 / 4);
  cast_bf16_kernel<<<256, 256, 0, stream>>>(projw, wp, 262144 / 4);
  cast_bf16_kernel<<<1024, 256, 0, stream>>>(fc1w, wf1, 1048576 / 4);
  cast_bf16_kernel<<<1024, 256, 0, stream>>>(fc2w, wf2, 1048576 / 4);
  bias_kernel<<<256, 256, 0, stream>>>(a_p, b_p, a_r, b_r, ridx, aidx, theta, biasbuf);

  ln_kernel<1><<<16384, 256, 0, stream>>>(x, n1g, n1b, lnbuf);
  gemm_bt_kernel<0><<<dim3(12, 512), 256, 0, stream>>>(lnbuf, wq, qkvb, qkvbuf, nullptr, 512, QKVLD);
  attn_kernel<<<16384, 64, 0, stream>>>(qkvbuf, biasbuf, attnbuf);
  gemm_bt_kernel<1><<<dim3(4, 512), 256, 0, stream>>>(attnbuf, wp, projb, out, x, 512, 512);
  ln_kernel<0><<<16384, 256, 0, stream>>>(out, n2g, n2b, lnbuf);
  gemm_bt_kernel<2><<<dim3(16, 512), 256, 0, stream>>>(lnbuf, wf1, fc1b, fc1buf, nullptr, 512, 2048);
  gemm_fc2_kernel<<<dim3(2, 512), 512, 0, stream>>>(fc1buf, wf2, fc2b, out, 2048, 512);
}